// Round 1
// baseline (18.354 us; speedup 1.0000x reference)
//
#include <hip/hip_runtime.h>

// Goodwin-Lotka-Volterra Euler integration with policy intervention.
// Strictly serial recurrence: a single thread runs the 200-step loop.
// The unclamped state propagates; clamped values are recorded.

__global__ void goodwin_volterra_kernel(const float* __restrict__ ps_ptr,
                                        const int* __restrict__ steps_ptr,
                                        float* __restrict__ out) {
    if (threadIdx.x != 0 || blockIdx.x != 0) return;

    constexpr float ALPHA = 0.1f;  // employment natural growth
    constexpr float BETA  = 0.5f;  // wage impact on employment
    constexpr float DELTA = 0.5f;  // employment impact on wages
    constexpr float GAMMA = 0.2f;  // wage decay
    constexpr float DT    = 0.1f;  // Euler step
    constexpr float X0    = 0.8f;
    constexpr float Y0    = 0.3f;

    const float ps    = fabsf(ps_ptr[0]);
    const int   steps = steps_ptr[0];

    float* __restrict__ xs = out;          // first `steps` elements
    float* __restrict__ ys = out + steps;  // next `steps` elements

    float x = X0;
    float y = Y0;

    for (int i = 0; i < steps; ++i) {
        // Mirror the reference's exact operation order for fp32 fidelity.
        float xy           = x * y;
        float intervention = -ps * xy;
        float dx = ALPHA * x - BETA * xy + intervention;
        float dy = DELTA * xy - GAMMA * y - intervention;
        float x_new = x + dx * DT;
        float y_new = y + dy * DT;

        // Record clamped values; propagate UNCLAMPED state.
        xs[i] = fminf(fmaxf(x_new, 0.0f), 1.0f);
        ys[i] = fminf(fmaxf(y_new, 0.0f), 1.0f);

        x = x_new;
        y = y_new;
    }
}

extern "C" void kernel_launch(void* const* d_in, const int* in_sizes, int n_in,
                              void* d_out, int out_size, void* d_ws, size_t ws_size,
                              hipStream_t stream) {
    const float* ps    = (const float*)d_in[0];  // policy_strength, 1 elem f32
    const int*   steps = (const int*)d_in[1];    // steps, 1 elem i32
    float*       out   = (float*)d_out;          // [2*steps] f32: xs then ys

    goodwin_volterra_kernel<<<1, 64, 0, stream>>>(ps, steps, out);
}

// Round 2
// 10.098 us; speedup vs baseline: 1.8177x; 1.8177x over previous
//
#include <hip/hip_runtime.h>

// Goodwin-Lotka-Volterra Euler integration with policy intervention.
// Strictly serial recurrence. Critical path minimized to 2 dependent VALU
// ops per step via constant folding:
//   x_new = a1*x - k1*xy,  y_new = a2*y + k2*xy,  xy = x*y
// where a1 = 1+ALPHA*DT, k1 = DT*(BETA+ps), a2 = 1-GAMMA*DT, k2 = DT*(DELTA+ps).
// Recorded (clamped) values go to LDS in-loop; the wave cooperatively
// writes them to global at the end. Unclamped state propagates.

#define GV_LDS_CAP 1024

__global__ void goodwin_volterra_kernel(const float* __restrict__ ps_ptr,
                                        const int* __restrict__ steps_ptr,
                                        float* __restrict__ out) {
    __shared__ float buf[2 * GV_LDS_CAP];

    const int tid   = threadIdx.x;
    const int steps = steps_ptr[0];
    const bool use_lds = (steps <= GV_LDS_CAP);

    if (tid == 0) {
        const float ps = fabsf(ps_ptr[0]);

        constexpr float ALPHA = 0.1f;
        constexpr float BETA  = 0.5f;
        constexpr float DELTA = 0.5f;
        constexpr float GAMMA = 0.2f;
        constexpr float DT    = 0.1f;

        const float a1 = 1.0f + ALPHA * DT;   // x retention
        const float a2 = 1.0f - GAMMA * DT;   // y retention
        const float k1 = DT * (BETA + ps);    // xy drain from x
        const float k2 = DT * (DELTA + ps);   // xy gain for y

        float x = 0.8f;
        float y = 0.3f;

        if (use_lds) {
            for (int i = 0; i < steps; ++i) {
                float xy = x * y;          // dep op 1
                float ax = a1 * x;         // off critical path (prev state)
                float ay = a2 * y;         // off critical path
                float xn = fmaf(-k1, xy, ax);  // dep op 2
                float yn = fmaf( k2, xy, ay);  // dep op 2 (parallel)
                buf[i]              = fminf(fmaxf(xn, 0.0f), 1.0f);
                buf[GV_LDS_CAP + i] = fminf(fmaxf(yn, 0.0f), 1.0f);
                x = xn;
                y = yn;
            }
        } else {
            for (int i = 0; i < steps; ++i) {
                float xy = x * y;
                float ax = a1 * x;
                float ay = a2 * y;
                float xn = fmaf(-k1, xy, ax);
                float yn = fmaf( k2, xy, ay);
                out[i]         = fminf(fmaxf(xn, 0.0f), 1.0f);
                out[steps + i] = fminf(fmaxf(yn, 0.0f), 1.0f);
                x = xn;
                y = yn;
            }
        }
    }

    if (use_lds) {
        __syncthreads();
        for (int i = tid; i < steps; i += 64) {
            out[i]         = buf[i];
            out[steps + i] = buf[GV_LDS_CAP + i];
        }
    }
}

extern "C" void kernel_launch(void* const* d_in, const int* in_sizes, int n_in,
                              void* d_out, int out_size, void* d_ws, size_t ws_size,
                              hipStream_t stream) {
    const float* ps    = (const float*)d_in[0];  // policy_strength, 1 elem f32
    const int*   steps = (const int*)d_in[1];    // steps, 1 elem i32
    float*       out   = (float*)d_out;          // [2*steps] f32: xs then ys

    goodwin_volterra_kernel<<<1, 64, 0, stream>>>(ps, steps, out);
}